// Round 5
// baseline (18.209 us; speedup 1.0000x reference)
//
#include <hip/hip_runtime.h>

// LogLinearModel: logits[b,j,v] = bias[v] + sum_{p=0..3} W[v, x[b,j-4+p]*4 + p]  (j>=4)
//                 logits[b,j,v] = bias[v]                                        (j<4)
// B=32, L=4096, N_SYM=64, D=256. Output fp32 (B,L,64) = 32MB -> store-BW-bound.
//
// R5: two dispatches. Prep kernel bakes the bf16 transposed+swizzled W table
// (32KB) into d_ws once; main blocks stage it with 8 coalesced dwordx4 loads +
// ds_write_b128 (no repack VALU, half the bytes) -> shorter pre-store prologue.

#define NSYM   64
#define CTX    4
#define DFEAT  256
#define LSEQ   4096
#define NPOS   (32 * LSEQ)          // 131072 positions
#define IPW    16                   // iterations per wave (4 positions each)
#define WAVES  4
#define POS_PER_BLOCK (WAVES * 64)  // 256 positions/block
#define BLOCKS (NPOS / POS_PER_BLOCK)   // 512
#define WT_WORDS (DFEAT * 32)       // 8192 u32 = 32KB

typedef float vfloat4 __attribute__((ext_vector_type(4)));

static __device__ __forceinline__ unsigned f2bf(float f) {
    unsigned u = __float_as_uint(f);
    return (u + 0x7fffu + ((u >> 16) & 1u)) >> 16;   // RNE
}

// ---- prep: W (64x256 f32) -> d_ws bf16 table, transposed + rotate-swizzled ----
// word[d*32 + m], m = ((q+d)&15)*2 + h, holds bf16 pair (v=4q+2h, v=4q+2h+1).
__global__ __launch_bounds__(256)
void prep_kernel(const float* __restrict__ W, unsigned int* __restrict__ wsw) {
    const int gid = blockIdx.x * 256 + threadIdx.x;   // 0..8191
    const int d = gid >> 5;
    const int m = gid & 31;
    const int h = m & 1;
    const int q = ((m >> 1) - d) & 15;
    const int v0 = 4 * q + 2 * h;
    const unsigned lo = f2bf(W[(v0    ) * DFEAT + d]);
    const unsigned hi = f2bf(W[(v0 + 1) * DFEAT + d]);
    wsw[gid] = lo | (hi << 16);
}

__global__ __launch_bounds__(256, 2)
void loglinear_kernel(const int* __restrict__ x,
                      const unsigned int* __restrict__ wsw,
                      const float* __restrict__ bias,
                      float* __restrict__ out) {
    __shared__ unsigned int wt[WT_WORDS];            // 32 KB, linear copy of wsw
    __shared__ int          xs[POS_PER_BLOCK + CTX]; // 260 ints

    const int t  = threadIdx.x;
    const int PB = blockIdx.x * POS_PER_BLOCK;
    const int jb = PB & (LSEQ - 1);   // j at block start (blocks never straddle batches)

    // ---- stage x chunk (coalesced) ----
    for (int k = t; k < POS_PER_BLOCK + CTX; k += 256) {
        xs[k] = (jb == 0 && k < CTX) ? 0 : x[PB - CTX + k];
    }

    // ---- stage Wt: 32KB linear, 8 x (dwordx4 load + ds_write_b128) ----
    {
        const uint4* src = reinterpret_cast<const uint4*>(wsw);
        uint4*       dst = reinterpret_cast<uint4*>(wt);
        #pragma unroll
        for (int r = 0; r < 8; ++r) {
            dst[r * 256 + t] = src[r * 256 + t];     // wave: 1KB contig read+write
        }
    }
    __syncthreads();

    const int lane = t & 63;
    const int wave = t >> 6;
    const int g = lane >> 4;      // position sub-index within wave-iter (0..3)
    const int q = lane & 15;      // v-quad (float4 of outputs)

    const float4 bq = reinterpret_cast<const float4*>(bias)[q];
    const vfloat4 b4 = {bq.x, bq.y, bq.z, bq.w};

    const int jbase = wave * 64;
    vfloat4* __restrict__ out4 = reinterpret_cast<vfloat4*>(out);
    const size_t outbase = (size_t)PB * 16 + q;

    #pragma unroll
    for (int ii = 0; ii < IPW; ++ii) {
        const int jloc = jbase + ii * 4 + g;
        vfloat4 acc = b4;
        if (jb + jloc >= CTX) {                      // j >= 4
            #pragma unroll
            for (int p = 0; p < CTX; ++p) {
                const int c = xs[jloc + p] * 4 + p;  // W column, 0..255
                const uint2 wp = *reinterpret_cast<const uint2*>(
                    &wt[c * 32 + (((q + c) & 15) << 1)]);
                acc.x += __uint_as_float(wp.x << 16);
                acc.y += __uint_as_float(wp.x & 0xffff0000u);
                acc.z += __uint_as_float(wp.y << 16);
                acc.w += __uint_as_float(wp.y & 0xffff0000u);
            }
        }
        out4[outbase + (size_t)jloc * 16] = acc;     // wave: contiguous 1KB
    }
}

extern "C" void kernel_launch(void* const* d_in, const int* in_sizes, int n_in,
                              void* d_out, int out_size, void* d_ws, size_t ws_size,
                              hipStream_t stream) {
    const int*   x   = (const int*)d_in[0];
    const float* W   = (const float*)d_in[1];
    const float* b   = (const float*)d_in[2];
    float*       out = (float*)d_out;
    unsigned int* wsw = (unsigned int*)d_ws;   // first 32KB: baked Wt table

    hipLaunchKernelGGL(prep_kernel, dim3(WT_WORDS / 256), dim3(256), 0, stream,
                       W, wsw);
    hipLaunchKernelGGL(loglinear_kernel, dim3(BLOCKS), dim3(256), 0, stream,
                       x, wsw, b, out);
}

// Round 6
// 15.429 us; speedup vs baseline: 1.1802x; 1.1802x over previous
//
#include <hip/hip_runtime.h>

// LogLinearModel: logits[b,j,v] = bias[v] + sum_{p=0..3} W[v, x[b,j-4+p]*4 + p]  (j>=4)
//                 logits[b,j,v] = bias[v]                                        (j<4)
// B=32, L=4096, N_SYM=64, D=256. Output fp32 (B,L,64) = 32MB -> store-BW-bound.
//
// R6: fp32 transposed table (64KB, unswizzled - row-covering b128 reads are
// minimum-bank-pass by construction) + packed 4-symbol windows xw[] (1 b32
// read/iter instead of 4). Inner loop: 1 ds_read_b32 + 4 ds_read_b128 +
// ~30 VALU + 1 dwordx4 store per KB. Exact fp32 (absmax 0).

#define NSYM   64
#define CTX    4
#define DFEAT  256
#define LSEQ   4096
#define NPOS   (32 * LSEQ)          // 131072 positions
#define IPW    16                   // iterations per wave (4 positions each)
#define POS_PER_BLOCK 256
#define BLOCKS (NPOS / POS_PER_BLOCK)   // 512

typedef float vfloat4 __attribute__((ext_vector_type(4)));

__global__ __launch_bounds__(256, 2)
void loglinear_kernel(const int* __restrict__ x,
                      const float* __restrict__ W,
                      const float* __restrict__ bias,
                      float* __restrict__ out) {
    __shared__ float    wt[DFEAT * NSYM];     // 64 KB: wt[c*64 + v] = W[v][c]
    __shared__ unsigned xw[POS_PER_BLOCK];    // packed context windows

    const int t  = threadIdx.x;
    const int PB = blockIdx.x * POS_PER_BLOCK;
    const int jb = PB & (LSEQ - 1);   // j at block start (blocks never straddle batches)

    // ---- xw[k]: symbols at positions PB+k-4 .. PB+k-1, one byte each ----
    {
        unsigned w = 0;
        #pragma unroll
        for (int p = 0; p < CTX; ++p) {
            const int idx = PB - CTX + t + p;       // coalesced across t
            const int sym = (idx >= 0) ? x[idx] : 0; // only block 0 clamps; guarded later anyway
            w |= (unsigned)sym << (8 * p);
        }
        xw[t] = w;
    }

    // ---- wt[c][v] = W[v][c], fp32 transpose (no repack, no swizzle) ----
    {
        const int v = t & 63;          // lane-distinct -> 2-way banked writes (free)
        const int chunk = t >> 6;      // 0..3
        #pragma unroll
        for (int it = 0; it < 16; ++it) {
            const int d0 = (chunk * 16 + it) * 4;
            const float4 wv = *reinterpret_cast<const float4*>(W + v * DFEAT + d0);
            wt[(d0    ) * 64 + v] = wv.x;
            wt[(d0 + 1) * 64 + v] = wv.y;
            wt[(d0 + 2) * 64 + v] = wv.z;
            wt[(d0 + 3) * 64 + v] = wv.w;
        }
    }
    __syncthreads();

    const int lane = t & 63;
    const int wave = t >> 6;
    const int g = lane >> 4;      // position sub-index within wave-iter (0..3)
    const int q = lane & 15;      // v-quad (float4 of outputs)

    const float4 bq = reinterpret_cast<const float4*>(bias)[q];
    const vfloat4 b4 = {bq.x, bq.y, bq.z, bq.w};

    const int jbase = wave * 64;
    vfloat4* __restrict__ outp =
        reinterpret_cast<vfloat4*>(out) + (size_t)(PB + jbase) * 16 + q;

    #pragma unroll
    for (int ii = 0; ii < IPW; ++ii) {
        const int jloc = jbase + ii * 4 + g;
        const unsigned w = xw[jloc];              // 1 b32, 16-lane broadcast
        vfloat4 acc = b4;
        if (jb + jloc >= CTX) {                   // j >= 4 (uniform except block 0, iter 0)
            #pragma unroll
            for (int p = 0; p < CTX; ++p) {
                const int sym = (w >> (8 * p)) & 0xff;   // v_bfe
                const vfloat4 wv = *reinterpret_cast<const vfloat4*>(
                    wt + sym * 256 + p * 64 + q * 4);    // b128, min-bank-pass
                acc += wv;                               // v_pk_add_f32 eligible
            }
        }
        outp[(ii * 4 + g) * 16] = acc;            // wave: contiguous 1KB
    }
}

extern "C" void kernel_launch(void* const* d_in, const int* in_sizes, int n_in,
                              void* d_out, int out_size, void* d_ws, size_t ws_size,
                              hipStream_t stream) {
    const int*   x   = (const int*)d_in[0];
    const float* W   = (const float*)d_in[1];
    const float* b   = (const float*)d_in[2];
    float*       out = (float*)d_out;

    hipLaunchKernelGGL(loglinear_kernel, dim3(BLOCKS), dim3(256), 0, stream,
                       x, W, b, out);
}